// Round 6
// baseline (175.375 us; speedup 1.0000x reference)
//
#include <hip/hip_runtime.h>
#include <math.h>

// SSIM fused single pass, v6.
// R5 post-mortem: acc state (88 fp32) > VGPR_Count(80) -> compiler banked
// accumulators in AGPRs, paying v_accvgpr_read/write around every scatter fma
// (~+130 VALU/iter, the entire model miss). v6:
//  * __launch_bounds__(128, 3): 170 unified regs/wave -> acc lives in arch
//    VGPRs, zero accvgpr traffic. 128-thread blocks (2 waves) for finer
//    scheduling; grid (2,23,48) = 4416 waves (~17/CU available).
//  * TY=23 (NJB=3, 33 iters) for more parallelism.
//  * Incremental pair-walk H-conv: no ab[]/sp[] temp arrays (v2f slices of
//    v4f window regs are free register subranges), keeps live set ~164.
// Keeps v4/v5's proven ordering: wave-private LDS rows, double-buffer (j&1),
// one __threadfence_block per iter, register prefetch of row j+1.

#define KW 11
#define RAD 5
#define IMG_W 512
#define IMG_H 512
#define TY 23                // output rows per wave tile; 33 iters = 3*11 phases
#define NJB 3
#define NV4 70               // 140 staged (a,b) pairs = 70 v4f per row buffer
#define C1F 0.0001f          // 0.01^2
#define C2F 0.0009f          // 0.03^2

typedef float v2f __attribute__((ext_vector_type(2)));
typedef float v4f __attribute__((ext_vector_type(4)));

__global__ __launch_bounds__(128, 3) void ssim_fused_kernel(
    const float* __restrict__ img1,
    const float* __restrict__ img2,
    float* __restrict__ out,
    float inv_n)
{
    __shared__ v4f rows[2][2][NV4];   // [wave][double-buffer][v4f = 2 pairs]
    __shared__ float red[2];

    const int tid  = threadIdx.x;
    const int lane = tid & 63;
    const int wvi  = tid >> 6;

    const int x0 = (blockIdx.x * 2 + wvi) * 128;   // wave's 128-col strip
    const int y0 = blockIdx.y * TY;                // wave's first output row

    const size_t pbase = (size_t)blockIdx.z * (size_t)(IMG_W * IMG_H);
    const float* __restrict__ p1 = img1 + pbase;
    const float* __restrict__ p2 = img2 + pbase;

    // Gaussian weights in double (matches float64 np reference), SGPR-pinned.
    float g[KW];
    {
        double t[KW];
        double s = 0.0;
        #pragma unroll
        for (int i = 0; i < KW; ++i) {
            const double c = (double)(i - RAD);
            t[i] = exp(-(c * c) / 4.5);   // 2*sigma^2 = 4.5
            s += t[i];
        }
        #pragma unroll
        for (int i = 0; i < KW; ++i) {
            const float gi = (float)(t[i] / s);
            g[i] = __int_as_float(__builtin_amdgcn_readfirstlane(__float_as_int(gi)));
        }
    }

    // Staged entries cover cols x0-6 .. x0+133 (140 entries, even base for
    // aligned float2 loads). Lane t owns entries {2t,2t+1}; lanes 0..5 also
    // stage halo entries {128+2t, 129+2t}.
    const int cm  = x0 - 6 + 2 * lane;                 // main col (even)
    const int cmc = min(max(cm, 0), IMG_W - 2);        // clamped, stays even
    const float mm0 = (cm     >= 0 && cm     < IMG_W) ? 1.f : 0.f;
    const float mm1 = (cm + 1 >= 0 && cm + 1 < IMG_W) ? 1.f : 0.f;
    const int ch  = x0 + 122 + 2 * lane;               // halo col (lanes 0..5)
    const int chc = min(max(ch, 0), IMG_W - 2);
    const float mh0 = (ch     < IMG_W) ? 1.f : 0.f;
    const float mh1 = (ch + 1 < IMG_W) ? 1.f : 0.f;

    // Load row (y0-RAD+j) into interleaved+masked (a0,b0,a1,b1) v4f regs.
    auto load_row = [&](int j, v4f& vm, v4f& vh) {
        const int ir = y0 - RAD + j;
        vm = (v4f){0.f, 0.f, 0.f, 0.f};
        vh = (v4f){0.f, 0.f, 0.f, 0.f};
        if ((unsigned)ir < (unsigned)IMG_H) {   // wave-uniform branch
            const float* r1 = p1 + ir * IMG_W;
            const float* r2 = p2 + ir * IMG_W;
            const v2f a = *reinterpret_cast<const v2f*>(r1 + cmc);
            const v2f b = *reinterpret_cast<const v2f*>(r2 + cmc);
            vm = (v4f){a.x * mm0, b.x * mm0, a.y * mm1, b.y * mm1};
            if (lane < 6) {
                const v2f ah = *reinterpret_cast<const v2f*>(r1 + chc);
                const v2f bh = *reinterpret_cast<const v2f*>(r2 + chc);
                vh = (v4f){ah.x * mh0, bh.x * mh0, ah.y * mh1, bh.y * mh1};
            }
        }
    };

    // V scatter accumulators for the thread's 2 columns (A=x0+2l, B=x0+2l+1):
    // slot s holds output row m with m%11==s.  (mu1,mu2) and (S,P) per px.
    v2f aMuA[KW], aSPA[KW], aMuB[KW], aSPB[KW];
    #pragma unroll
    for (int s = 0; s < KW; ++s) {
        aMuA[s] = (v2f){0.f, 0.f}; aSPA[s] = (v2f){0.f, 0.f};
        aMuB[s] = (v2f){0.f, 0.f}; aSPB[s] = (v2f){0.f, 0.f};
    }

    v4f curm, curh;
    load_row(0, curm, curh);

    float acc = 0.f;

    #pragma clang loop unroll(disable)
    for (int jb = 0; jb < NJB; ++jb) {
        #pragma unroll
        for (int P = 0; P < KW; ++P) {
            const int j   = jb * KW + P;        // 0..32
            const int buf = j & 1;
            v4f* __restrict__ wrow = rows[wvi][buf];

            // ---- stage row j (regs -> wave-private LDS) ----
            wrow[lane] = curm;                          // ds_write_b128
            if (lane < 6) wrow[64 + lane] = curh;
            __threadfence_block();   // wave-local lgkm drain; orders W_j < R_j
                                     // and (via F_{j+1}) R_j < W_{j+2}

            // ---- prefetch row j+1 (latency covered by this iter's math) ----
            load_row(j + 1, curm, curh);

            // ---- read the window: v4f slots lane..lane+6 (pairs 2l..2l+13) --
            v4f e[7];
            #pragma unroll
            for (int r = 0; r < 7; ++r) e[r] = wrow[lane + r];   // ds_read_b128

            // ---- incremental pair walk: pairs i=1..12 (rel 2l) ----
            // col A (x0+2l)   uses pairs 1..11 with weight g[i-1]
            // col B (x0+2l+1) uses pairs 2..12 with weight g[i-2]
            v2f hMuA = (v2f){0.f, 0.f}, hSPA = (v2f){0.f, 0.f};
            v2f hMuB = (v2f){0.f, 0.f}, hSPB = (v2f){0.f, 0.f};
            #pragma unroll
            for (int i = 1; i <= 12; ++i) {
                const v4f q = e[i >> 1];
                const v2f t = (i & 1) ? (v2f){q.z, q.w} : (v2f){q.x, q.y};
                const v2f spv = (v2f){fmaf(t.x, t.x, t.y * t.y), t.x * t.y};
                if (i <= 11) {
                    const v2f gA = (v2f){g[i - 1], g[i - 1]};
                    hMuA = __builtin_elementwise_fma(gA, t,   hMuA);
                    hSPA = __builtin_elementwise_fma(gA, spv, hSPA);
                }
                if (i >= 2) {
                    const v2f gB = (v2f){g[i - 2], g[i - 2]};
                    hMuB = __builtin_elementwise_fma(gB, t,   hMuB);
                    hSPB = __builtin_elementwise_fma(gB, spv, hSPB);
                }
            }

            // ---- vertical scatter; slot s==P gets its FIRST tap: assign ----
            #pragma unroll
            for (int s = 0; s < KW; ++s) {
                const float wt = g[(P - s + KW) % KW];
                const v2f wv2 = (v2f){wt, wt};
                if (s == P) {
                    aMuA[s] = wv2 * hMuA;  aSPA[s] = wv2 * hSPA;
                    aMuB[s] = wv2 * hMuB;  aSPB[s] = wv2 * hSPB;
                } else {
                    aMuA[s] = __builtin_elementwise_fma(wv2, hMuA, aMuA[s]);
                    aSPA[s] = __builtin_elementwise_fma(wv2, hSPA, aSPA[s]);
                    aMuB[s] = __builtin_elementwise_fma(wv2, hMuB, aMuB[s]);
                    aSPB[s] = __builtin_elementwise_fma(wv2, hSPB, aSPB[s]);
                }
            }

            // ---- emit output row oy = y0 + j - 10 from slot (P+1)%11 ----
            const int oy = y0 + j - 2 * RAD;
            if (j >= 2 * RAD && oy < IMG_H) {   // wave-uniform
                const int e2 = (P + 1) % KW;
                #pragma unroll
                for (int px = 0; px < 2; ++px) {
                    const v2f mu = px ? aMuB[e2] : aMuA[e2];
                    const v2f SP = px ? aSPB[e2] : aSPA[e2];
                    const v2f musq = mu * mu;
                    const float mu12  = mu.x * mu.y;
                    const float musum = musq.x + musq.y;
                    const float ssum  = SP.x - musum;        // sigma1^2+sigma2^2
                    const float s12   = SP.y - mu12;         // sigma12
                    const float num = fmaf(2.f, mu12, C1F) * fmaf(2.f, s12, C2F);
                    const float den = (musum + C1F) * (ssum + C2F);
                    acc = fmaf(num, __builtin_amdgcn_rcpf(den), acc);
                }
            }
        }
    }

    // ---- block reduction, one atomic per block ----
    #pragma unroll
    for (int off = 32; off > 0; off >>= 1)
        acc += __shfl_xor(acc, off, 64);
    if (lane == 0) red[wvi] = acc;
    __syncthreads();
    if (tid == 0) {
        const float s = red[0] + red[1];
        atomicAdd(out, s * inv_n);
    }
}

extern "C" void kernel_launch(void* const* d_in, const int* in_sizes, int n_in,
                              void* d_out, int out_size, void* d_ws, size_t ws_size,
                              hipStream_t stream) {
    (void)in_sizes; (void)n_in; (void)d_ws; (void)ws_size;
    const float* img1 = (const float*)d_in[0];
    const float* img2 = (const float*)d_in[1];
    float* out = (float*)d_out;

    // d_out is re-poisoned to 0xAA before every launch; zero it (capture-safe).
    hipMemsetAsync(out, 0, (size_t)out_size * sizeof(float), stream);

    const float inv_n = 1.0f / (16.0f * 3.0f * 512.0f * 512.0f);
    // x: 2 blocks x 2 waves = 4 col-strips; y: 23 tiles of 23 rows (tail
    // masked); z: 48 planes.  2208 blocks, 4416 waves.
    dim3 grid(2, 23, 48);
    ssim_fused_kernel<<<grid, dim3(128, 1, 1), 0, stream>>>(img1, img2, out, inv_n);
}

// Round 7
// 169.553 us; speedup vs baseline: 1.0343x; 1.0343x over previous
//
#include <hip/hip_runtime.h>
#include <math.h>

// SSIM fused single pass, v7 = v5 structure + two fixes.
// R6 post-mortem: __launch_bounds__(128,3) rounded to 4 waves/EU for 2-wave
// workgroups -> 128-reg budget -> AGPR banking persisted (VGPR_Count 72+~56
// acc = 128). v7 uses 4-wave (256-thread) workgroups with
// __launch_bounds__(256,3): 3 waves/EU is exactly achievable (1 wave/EU per
// WG), budget ~168 arch regs -> the 88-float scatter accumulator state stays
// in arch VGPRs, no v_accvgpr traffic (verify: VGPR_Count >= 130).
// TY=23 (NJB=3) raises the grid to 1104 blocks / 4416 waves so the 12
// waves/CU allowed by the launch bound are actually available.
// Everything else is v5 verbatim: 2 cols/thread, 4 vertical quantities
// (mu1, mu2, S=E[x^2]+E[y^2], P=E[xy]), v4f LDS rows (ds_read_b128),
// wave-private double-buffered staging + one __threadfence_block per iter,
// register prefetch of row j+1, rcp division (err ~1e-7 << 2.6e-4).

#define KW 11
#define RAD 5
#define IMG_W 512
#define IMG_H 512
#define TY 23                // output rows per wave tile; 33 iters = 3*11 phases
#define NJB 3
#define NV4 70               // 140 staged (a,b) pairs = 70 v4f per row buffer
#define C1F 0.0001f          // 0.01^2
#define C2F 0.0009f          // 0.03^2

typedef float v2f __attribute__((ext_vector_type(2)));
typedef float v4f __attribute__((ext_vector_type(4)));

__global__ __launch_bounds__(256, 3) void ssim_fused_kernel(
    const float* __restrict__ img1,
    const float* __restrict__ img2,
    float* __restrict__ out,
    float inv_n)
{
    __shared__ v4f rows[4][2][NV4];   // [wave][double-buffer][v4f = 2 pairs]
    __shared__ float red[4];

    const int tid  = threadIdx.x;
    const int lane = tid & 63;
    const int wvi  = tid >> 6;

    const int x0 = wvi * 128;              // wave's 128-col strip
    const int y0 = blockIdx.x * TY;        // wave's first output row

    const size_t pbase = (size_t)blockIdx.y * (size_t)(IMG_W * IMG_H);
    const float* __restrict__ p1 = img1 + pbase;
    const float* __restrict__ p2 = img2 + pbase;

    // Gaussian weights in double (matches float64 np reference), SGPR-pinned.
    float g[KW];
    {
        double t[KW];
        double s = 0.0;
        #pragma unroll
        for (int i = 0; i < KW; ++i) {
            const double c = (double)(i - RAD);
            t[i] = exp(-(c * c) / 4.5);   // 2*sigma^2 = 4.5
            s += t[i];
        }
        #pragma unroll
        for (int i = 0; i < KW; ++i) {
            const float gi = (float)(t[i] / s);
            g[i] = __int_as_float(__builtin_amdgcn_readfirstlane(__float_as_int(gi)));
        }
    }

    // Staged entries cover cols x0-6 .. x0+133 (140 entries, even base for
    // aligned float2 loads). Lane t owns entries {2t,2t+1}; lanes 0..5 also
    // stage halo entries {128+2t, 129+2t}.
    const int cm  = x0 - 6 + 2 * lane;                 // main col (even)
    const int cmc = min(max(cm, 0), IMG_W - 2);        // clamped, stays even
    const float mm0 = (cm     >= 0 && cm     < IMG_W) ? 1.f : 0.f;
    const float mm1 = (cm + 1 >= 0 && cm + 1 < IMG_W) ? 1.f : 0.f;
    const int ch  = x0 + 122 + 2 * lane;               // halo col (lanes 0..5)
    const int chc = min(max(ch, 0), IMG_W - 2);
    const float mh0 = (ch     < IMG_W) ? 1.f : 0.f;
    const float mh1 = (ch + 1 < IMG_W) ? 1.f : 0.f;

    // Load row (y0-RAD+j) into interleaved+masked (a0,b0,a1,b1) v4f regs.
    auto load_row = [&](int j, v4f& vm, v4f& vh) {
        const int ir = y0 - RAD + j;
        vm = (v4f){0.f, 0.f, 0.f, 0.f};
        vh = (v4f){0.f, 0.f, 0.f, 0.f};
        if ((unsigned)ir < (unsigned)IMG_H) {   // wave-uniform branch
            const float* r1 = p1 + ir * IMG_W;
            const float* r2 = p2 + ir * IMG_W;
            const v2f a = *reinterpret_cast<const v2f*>(r1 + cmc);
            const v2f b = *reinterpret_cast<const v2f*>(r2 + cmc);
            vm = (v4f){a.x * mm0, b.x * mm0, a.y * mm1, b.y * mm1};
            if (lane < 6) {
                const v2f ah = *reinterpret_cast<const v2f*>(r1 + chc);
                const v2f bh = *reinterpret_cast<const v2f*>(r2 + chc);
                vh = (v4f){ah.x * mh0, bh.x * mh0, ah.y * mh1, bh.y * mh1};
            }
        }
    };

    // V scatter accumulators for the thread's 2 columns (A=x0+2l, B=x0+2l+1):
    // slot s holds output row m with m%11==s.  (mu1,mu2) and (S,P) per px.
    v2f aMuA[KW], aSPA[KW], aMuB[KW], aSPB[KW];
    #pragma unroll
    for (int s = 0; s < KW; ++s) {
        aMuA[s] = (v2f){0.f, 0.f}; aSPA[s] = (v2f){0.f, 0.f};
        aMuB[s] = (v2f){0.f, 0.f}; aSPB[s] = (v2f){0.f, 0.f};
    }

    v4f curm, curh;
    load_row(0, curm, curh);

    float acc = 0.f;

    #pragma clang loop unroll(disable)
    for (int jb = 0; jb < NJB; ++jb) {
        #pragma unroll
        for (int P = 0; P < KW; ++P) {
            const int j   = jb * KW + P;        // 0..32
            const int buf = j & 1;
            v4f* __restrict__ wrow = rows[wvi][buf];

            // ---- stage row j (regs -> wave-private LDS) ----
            wrow[lane] = curm;                          // ds_write_b128
            if (lane < 6) wrow[64 + lane] = curh;
            __threadfence_block();   // wave-local lgkm drain; orders W_j < R_j
                                     // and (via F_{j+1}) R_j < W_{j+2}

            // ---- prefetch row j+1 (latency covered by this iter's math) ----
            load_row(j + 1, curm, curh);

            // ---- read the window: v4f slots lane..lane+6 (pairs 2l..2l+13) --
            v4f e[7];
            #pragma unroll
            for (int r = 0; r < 7; ++r) e[r] = wrow[lane + r];   // ds_read_b128

            // ---- incremental pair walk: pairs i=1..12 (rel 2l) ----
            // col A (x0+2l)   uses pairs 1..11 with weight g[i-1]
            // col B (x0+2l+1) uses pairs 2..12 with weight g[i-2]
            v2f hMuA = (v2f){0.f, 0.f}, hSPA = (v2f){0.f, 0.f};
            v2f hMuB = (v2f){0.f, 0.f}, hSPB = (v2f){0.f, 0.f};
            #pragma unroll
            for (int i = 1; i <= 12; ++i) {
                const v4f q = e[i >> 1];
                const v2f t = (i & 1) ? (v2f){q.z, q.w} : (v2f){q.x, q.y};
                const v2f spv = (v2f){fmaf(t.x, t.x, t.y * t.y), t.x * t.y};
                if (i <= 11) {
                    const v2f gA = (v2f){g[i - 1], g[i - 1]};
                    hMuA = __builtin_elementwise_fma(gA, t,   hMuA);
                    hSPA = __builtin_elementwise_fma(gA, spv, hSPA);
                }
                if (i >= 2) {
                    const v2f gB = (v2f){g[i - 2], g[i - 2]};
                    hMuB = __builtin_elementwise_fma(gB, t,   hMuB);
                    hSPB = __builtin_elementwise_fma(gB, spv, hSPB);
                }
            }

            // ---- vertical scatter; slot s==P gets its FIRST tap: assign ----
            #pragma unroll
            for (int s = 0; s < KW; ++s) {
                const float wt = g[(P - s + KW) % KW];
                const v2f wv2 = (v2f){wt, wt};
                if (s == P) {
                    aMuA[s] = wv2 * hMuA;  aSPA[s] = wv2 * hSPA;
                    aMuB[s] = wv2 * hMuB;  aSPB[s] = wv2 * hSPB;
                } else {
                    aMuA[s] = __builtin_elementwise_fma(wv2, hMuA, aMuA[s]);
                    aSPA[s] = __builtin_elementwise_fma(wv2, hSPA, aSPA[s]);
                    aMuB[s] = __builtin_elementwise_fma(wv2, hMuB, aMuB[s]);
                    aSPB[s] = __builtin_elementwise_fma(wv2, hSPB, aSPB[s]);
                }
            }

            // ---- emit output row oy = y0 + j - 10 from slot (P+1)%11 ----
            const int oy = y0 + j - 2 * RAD;
            if (j >= 2 * RAD && oy < IMG_H) {   // wave-uniform
                const int e2 = (P + 1) % KW;
                #pragma unroll
                for (int px = 0; px < 2; ++px) {
                    const v2f mu = px ? aMuB[e2] : aMuA[e2];
                    const v2f SP = px ? aSPB[e2] : aSPA[e2];
                    const v2f musq = mu * mu;
                    const float mu12  = mu.x * mu.y;
                    const float musum = musq.x + musq.y;
                    const float ssum  = SP.x - musum;        // sigma1^2+sigma2^2
                    const float s12   = SP.y - mu12;         // sigma12
                    const float num = fmaf(2.f, mu12, C1F) * fmaf(2.f, s12, C2F);
                    const float den = (musum + C1F) * (ssum + C2F);
                    acc = fmaf(num, __builtin_amdgcn_rcpf(den), acc);
                }
            }
        }
    }

    // ---- block reduction, one atomic per block ----
    #pragma unroll
    for (int off = 32; off > 0; off >>= 1)
        acc += __shfl_xor(acc, off, 64);
    if (lane == 0) red[wvi] = acc;
    __syncthreads();
    if (tid == 0) {
        const float s = red[0] + red[1] + red[2] + red[3];
        atomicAdd(out, s * inv_n);
    }
}

extern "C" void kernel_launch(void* const* d_in, const int* in_sizes, int n_in,
                              void* d_out, int out_size, void* d_ws, size_t ws_size,
                              hipStream_t stream) {
    (void)in_sizes; (void)n_in; (void)d_ws; (void)ws_size;
    const float* img1 = (const float*)d_in[0];
    const float* img2 = (const float*)d_in[1];
    float* out = (float*)d_out;

    // d_out is re-poisoned to 0xAA before every launch; zero it (capture-safe).
    hipMemsetAsync(out, 0, (size_t)out_size * sizeof(float), stream);

    const float inv_n = 1.0f / (16.0f * 3.0f * 512.0f * 512.0f);
    // x: 23 y-tiles of 23 rows (tail masked); y: 48 planes.
    // 1104 blocks x 4 waves (4 col-strips in-block) = 4416 waves.
    dim3 grid(23, 48, 1);
    ssim_fused_kernel<<<grid, dim3(256, 1, 1), 0, stream>>>(img1, img2, out, inv_n);
}